// Round 1
// baseline (115.433 us; speedup 1.0000x reference)
//
#include <hip/hip_runtime.h>

// CRF-RNN (C=2) on 56x56. Math reduction:
//   softmax over 2 channels -> s = sigmoid(q1-q0), softmax_out = [1-s; s]
//   spatial_out[1] = (K_sp@s)/norm_sp ; spatial_out[0] = 1 - spatial_out[1]
//   q1-q0 next = (2u-1) - alpha - beta*(K_sp@s)/n_sp - gamma*(K_bl@s)/n_bl
// with alpha,beta,gamma scalars from the 2x2 weight matrices.
// Per iteration: one fused pass over all 3136x3136 pairs computing both
// Gaussian kernels on the fly (shared r^2) and accumulating t_sp,t_bl.

namespace {

constexpr int NPIX  = 3136;
constexpr int WIMG  = 56;
constexpr int NCH   = 8;             // i-chunks
constexpr int CHUNK = NPIX / NCH;    // 392
constexpr int JT    = 64;            // j's per block
constexpr int NJT   = NPIX / JT;     // 49

constexpr float LOG2E = 1.4426950408889634f;
// k_sp = exp(-r2/18)            -> exp2(r2*C1)
// k_bl = exp(-r2/51200 - dg2/6) -> exp2(r2*C2 + dg2*C3)
constexpr float C1 = -LOG2E / 18.0f;
constexpr float C2 = -LOG2E / 51200.0f;
constexpr float C3 = -LOG2E / 6.0f;

__device__ __forceinline__ void coeffs(const float* __restrict__ sp,
                                       const float* __restrict__ bl,
                                       const float* __restrict__ cm,
                                       float& alpha, float& beta, float& gamma) {
    // e = compat[1,:] - compat[0,:]
    const float e0 = cm[2] - cm[0];
    const float e1 = cm[3] - cm[1];
    alpha = e0 * (sp[0] + bl[0]) + e1 * (sp[2] + bl[2]);
    beta  = e0 * (sp[1] - sp[0]) + e1 * (sp[3] - sp[2]);
    gamma = e0 * (bl[1] - bl[0]) + e1 * (bl[3] - bl[2]);
}

template <bool FIRST>
__global__ __launch_bounds__(256) void crf_iter(
    const float* __restrict__ inp,   // [2*3136]: u, gray_raw
    const float* __restrict__ spw, const float* __restrict__ blw,
    const float* __restrict__ cmw,
    const float* __restrict__ ptsp, const float* __restrict__ ptbl,  // prev partials [8][3136]
    float* __restrict__ otsp, float* __restrict__ otbl,              // out partials  [8][3136]
    float* __restrict__ nspp, float* __restrict__ nblp)              // norm partials [8][3136]
{
    __shared__ float s_lds[CHUNK];
    __shared__ float g_lds[CHUNK];

    const int jt = blockIdx.x / NCH;
    const int ic = blockIdx.x - jt * NCH;
    const int t  = threadIdx.x;

    float alpha, beta, gamma;
    coeffs(spw, blw, cmw, alpha, beta, gamma);

    // ---- stage s and g for this i-chunk (recompute s from previous partials)
    const int ibase = ic * CHUNK;
    for (int m = t; m < CHUNK; m += 256) {
        const int i = ibase + m;
        const float u = inp[i];
        const float g = inp[NPIX + i] * 255.0f;
        float s;
        if (FIRST) {
            s = u;  // iteration 0 uses unaries directly: [1-u; u]
        } else {
            float tsp = 0.f, tbl = 0.f, nsp = 0.f, nbl = 0.f;
#pragma unroll
            for (int c = 0; c < NCH; ++c) {
                tsp += ptsp[c * NPIX + i];
                tbl += ptbl[c * NPIX + i];
                nsp += nspp[c * NPIX + i];
                nbl += nblp[c * NPIX + i];
            }
            const float d = (2.f * u - 1.f) - alpha - beta * (tsp / nsp) - gamma * (tbl / nbl);
            s = 1.f / (1.f + __expf(-d));
        }
        s_lds[m] = s;
        g_lds[m] = g;
    }
    __syncthreads();

    // ---- main pair loop: 4 lanes per output pixel j, strided over i-chunk
    const int j   = jt * JT + (t >> 2);
    const int sub = t & 3;
    const float xj = (float)(j % WIMG);
    const float yj = (float)(j / WIMG);
    const float gj = inp[NPIX + j] * 255.0f;

    float tsp = 0.f, tbl = 0.f, nsp = 0.f, nbl = 0.f;
    const int i0 = ibase + sub;
    float xi = (float)(i0 % WIMG);
    float yi = (float)(i0 / WIMG);

    for (int m = sub; m < CHUNK; m += 4) {
        const float s  = s_lds[m];
        const float g  = g_lds[m];
        const float dx = xi - xj;
        const float dy = yi - yj;
        const float r2 = fmaf(dx, dx, dy * dy);
        const float dg = g - gj;
        const float esp = __builtin_amdgcn_exp2f(r2 * C1);
        const float ebl = __builtin_amdgcn_exp2f(fmaf(dg * C3, dg, r2 * C2));
        tsp = fmaf(s, esp, tsp);
        tbl = fmaf(s, ebl, tbl);
        if (FIRST) { nsp += esp; nbl += ebl; }
        xi += 4.0f;
        if (xi >= 56.0f) { xi -= 56.0f; yi += 1.0f; }
    }

    // reduce across the 4 cooperating lanes (aligned groups within a wave)
    tsp += __shfl_xor(tsp, 1); tsp += __shfl_xor(tsp, 2);
    tbl += __shfl_xor(tbl, 1); tbl += __shfl_xor(tbl, 2);
    if (FIRST) {
        nsp += __shfl_xor(nsp, 1); nsp += __shfl_xor(nsp, 2);
        nbl += __shfl_xor(nbl, 1); nbl += __shfl_xor(nbl, 2);
    }
    if (sub == 0) {
        otsp[ic * NPIX + j] = tsp;
        otbl[ic * NPIX + j] = tbl;
        if (FIRST) {
            nspp[ic * NPIX + j] = nsp;
            nblp[ic * NPIX + j] = nbl;
        }
    }
}

__global__ __launch_bounds__(256) void crf_final(
    const float* __restrict__ inp,
    const float* __restrict__ spw, const float* __restrict__ blw,
    const float* __restrict__ cmw,
    const float* __restrict__ ptsp, const float* __restrict__ ptbl,
    const float* __restrict__ nspp, const float* __restrict__ nblp,
    float* __restrict__ out)
{
    const int j = blockIdx.x * 256 + threadIdx.x;
    if (j >= NPIX) return;
    float alpha, beta, gamma;
    coeffs(spw, blw, cmw, alpha, beta, gamma);
    float tsp = 0.f, tbl = 0.f, nsp = 0.f, nbl = 0.f;
#pragma unroll
    for (int c = 0; c < NCH; ++c) {
        tsp += ptsp[c * NPIX + j];
        tbl += ptbl[c * NPIX + j];
        nsp += nspp[c * NPIX + j];
        nbl += nblp[c * NPIX + j];
    }
    const float u = inp[j];
    const float d = (2.f * u - 1.f) - alpha - beta * (tsp / nsp) - gamma * (tbl / nbl);
    out[j] = 1.f / (1.f + __expf(-d));
}

}  // namespace

extern "C" void kernel_launch(void* const* d_in, const int* in_sizes, int n_in,
                              void* d_out, int out_size, void* d_ws, size_t ws_size,
                              hipStream_t stream) {
    const float* inp = (const float*)d_in[0];
    const float* spw = (const float*)d_in[1];
    const float* blw = (const float*)d_in[2];
    const float* cmw = (const float*)d_in[3];
    float* ws = (float*)d_ws;

    const int P = NCH * NPIX;  // 25088 floats per partial array
    float* tsp0 = ws + 0 * P;
    float* tbl0 = ws + 1 * P;
    float* tsp1 = ws + 2 * P;
    float* tbl1 = ws + 3 * P;
    float* nspp = ws + 4 * P;
    float* nblp = ws + 5 * P;

    const dim3 grid(NJT * NCH);  // 392 blocks
    const dim3 blk(256);

    // iteration 0: s = u, also produces norm partials
    crf_iter<true><<<grid, blk, 0, stream>>>(inp, spw, blw, cmw,
                                             tsp0, tbl0,       // unused
                                             tsp0, tbl0, nspp, nblp);
    float* bufT[2] = {tsp0, tsp1};
    float* bufB[2] = {tbl0, tbl1};
    for (int k = 1; k < 10; ++k) {
        float* pt = bufT[(k + 1) & 1];
        float* pb = bufB[(k + 1) & 1];
        float* ot = bufT[k & 1];
        float* ob = bufB[k & 1];
        crf_iter<false><<<grid, blk, 0, stream>>>(inp, spw, blw, cmw,
                                                  pt, pb, ot, ob, nspp, nblp);
    }
    // after k=9 the live buffer is index 1
    crf_final<<<dim3((NPIX + 255) / 256), blk, 0, stream>>>(
        inp, spw, blw, cmw, bufT[1], bufB[1], nspp, nblp, (float*)d_out);
}